// Round 6
// baseline (160.902 us; speedup 1.0000x reference)
//
#include <hip/hip_runtime.h>

#define RES 320
#define CELLS (RES * RES)
#define MDIM 640      // 2*RES (Re/Im stacked)
#define NCOLS 10240   // 32 batches * RES

typedef __attribute__((ext_vector_type(8))) short short8;
typedef __attribute__((ext_vector_type(4))) float f32x4;

// round-to-nearest-even f32 -> bf16 bits (all values finite here)
static __device__ __forceinline__ short f2bf(float f) {
    unsigned u = __builtin_bit_cast(unsigned, f);
    unsigned r = (u + 0x7fffu + ((u >> 16) & 1u)) >> 16;
    return (short)r;
}

#define GLD16(g, l) __builtin_amdgcn_global_load_lds(                        \
    (const __attribute__((address_space(1))) void*)(g),                      \
    (__attribute__((address_space(3))) void*)(l), 16, 0, 0)

// ---------------------------------------------------------------------------
// Wave-level run-segmented atomic add: combines contiguous equal-key runs,
// one atomic per run (key < 0 => no atomic). MUST be called convergently by
// all 64 lanes. Degenerate (skipped-trajectory) lanes are contiguous in I and
// share identical keys -> 1 atomic per run per wave.
// ---------------------------------------------------------------------------
__device__ __forceinline__ void seg_atomic_add(float* base, int key, float val, int lane) {
    int prev = __shfl_up(key, 1);
    bool head = (lane == 0) || (prev != key);
    unsigned long long hb = __ballot(head);
    unsigned long long below = (lane == 63) ? hb : (hb & ((1ULL << (lane + 1)) - 1ULL));
    int run_start = 63 - __clzll(below);
#pragma unroll
    for (int d = 1; d < 64; d <<= 1) {
        float o = __shfl_up(val, d);
        if (lane - d >= run_start) val += o;
    }
    bool tail = (lane == 63) || ((hb >> (lane + 1)) & 1ULL);
    if (tail && key >= 0) atomicAdd(base + key, val);
}

// ---------------------------------------------------------------------------
// Build M9, banded NJ=1 + halo planes. Band j (320 blocks): points with J=j,
// thread tid = I. In-bounds targets of NORMAL points have cy in {j-1, j}
// (trajectory row j maps to y=j-0.5) -> LDS window acc[9][2][320]; lanes =
// consecutive I = consecutive cx = conflict-free ds_add. Flush: both window
// rows go to per-band halo planes via plain float4 stores (no atomics).
// Out-of-window contributions (degenerate points -> cells 159/160) go through
// a ballot-guarded CONVERGENT seg-atomic per pair: lanes sharing a key
// combine to one atomic (the previous per-lane lazy flush serialized up to
// 320-way on the all-degenerate bands j in [120,160]).
// ---------------------------------------------------------------------------
__global__ __launch_bounds__(320) void build_m9(const float* __restrict__ traj,
                                                float* __restrict__ hal0,
                                                float* __restrict__ hal1,
                                                float* __restrict__ M9s) {
    __shared__ float acc[9 * 2 * RES];
    int j = blockIdx.x;     // band = J row
    int tid = threadIdx.x;  // = I
    int lane = tid & 63;
    for (int i = tid; i < 9 * 2 * RES; i += 320) acc[i] = 0.f;
    __syncthreads();

    const float2 t = ((const float2*)traj)[(size_t)tid * RES + j];
    float x = ((t.x * (2.0f / RES) + 1.0f) * RES - 1.0f) * 0.5f;
    float y = ((t.y * (2.0f / RES) + 1.0f) * RES - 1.0f) * 0.5f;
    float x0f = floorf(x), y0f = floorf(y);
    float fx = x - x0f, fy = y - y0f;
    int x0 = (int)x0f, y0 = (int)y0f;

    const int ox[4] = {0, 1, 0, 1};
    const int oy[4] = {0, 0, 1, 1};
    float w[4] = {(1.f - fx) * (1.f - fy), fx * (1.f - fy), (1.f - fx) * fy, fx * fy};
    int cxv[4], cyv[4];
    bool v[4];
#pragma unroll
    for (int k = 0; k < 4; k++) {
        int cx = x0 + ox[k], cy = y0 + oy[k];
        v[k] = (cx >= 0) && (cx < RES) && (cy >= 0) && (cy < RES);
        cxv[k] = cx;
        cyv[k] = cy;
    }
#pragma unroll
    for (int jc = 0; jc < 4; jc++) {
#pragma unroll
        for (int ic = 0; ic < 4; ic++) {
            int slot = (oy[ic] - oy[jc] + 1) * 3 + (ox[ic] - ox[jc] + 1);
            bool valid = v[ic] && v[jc];
            float wv = w[jc] * w[ic];
            int wr = cyv[jc] - j + 1;  // in-window row if 0 or 1
            bool inwin = valid && ((unsigned)wr < 2u);
            if (inwin) atomicAdd(&acc[(slot * 2 + wr) * RES + cxv[jc]], wv);
            bool sp = valid && !inwin;
            if (__ballot(sp))  // wave-uniform guard -> convergent call
                seg_atomic_add(M9s, sp ? slot * CELLS + cyv[jc] * RES + cxv[jc] : -1,
                               wv, lane);
        }
    }
    __syncthreads();
    // Flush both window rows to halo planes: plain float4 stores (full rows,
    // including zeros -> halos need no pre-zeroing).
    for (int i = tid; i < 9 * 2 * (RES / 4); i += 320) {
        int q = i % (RES / 4);
        int sr = i / (RES / 4);   // 0..17
        int wrow = sr & 1;
        int slot = sr >> 1;
        float4 v4 = *(const float4*)&acc[(slot * 2 + wrow) * RES + q * 4];
        float* hal = wrow ? hal1 : hal0;
        *(float4*)&hal[((size_t)j * 9 + slot) * RES + q * 4] = v4;
    }
}

// ---------------------------------------------------------------------------
// Compose M9[slot][cy][x] = hal1[cy] + hal0[cy+1] + M9s (spill), and also
// generate F1 (fused: same pass, disjoint index ranges).
// F1[m'][y'] bf16, 640x640: block matrix [[Fr,-Fi],[Fi,Fr]] of
// F[u,y] = (-1)^(u+y) exp(+2*pi*i*u*y/RES); stage-1 A and stage-2 B operand.
// ---------------------------------------------------------------------------
__global__ __launch_bounds__(256) void merge_m9_F1(float* __restrict__ M9,
                                                   const float* __restrict__ hal0,
                                                   const float* __restrict__ hal1,
                                                   const float* __restrict__ M9s,
                                                   short* __restrict__ F1) {
    int i = blockIdx.x * 256 + threadIdx.x;
    if (i < 9 * CELLS) {
        int slot = i / CELLS;
        int rem = i - slot * CELLS;
        int cy = rem / RES;
        int x = rem - cy * RES;
        float s = hal1[((size_t)cy * 9 + slot) * RES + x] + M9s[i];
        if (cy + 1 < RES) s += hal0[((size_t)(cy + 1) * 9 + slot) * RES + x];
        M9[i] = s;
    }
    if (i < MDIM * MDIM) {
        int mp = i / MDIM, yp = i % MDIM;
        int cm = mp >= RES, cyy = yp >= RES;
        int m = mp - RES * cm, y = yp - RES * cyy;
        int r = (m * y) % RES;
        float s, c;
        sincospif((float)r * (2.0f / RES), &s, &c);
        float sign = ((m + y) & 1) ? -1.0f : 1.0f;
        float fr = sign * c, fi = sign * s;
        float val = (cm == 0) ? (cyy == 0 ? fr : -fi) : (cyy == 0 ? fi : fr);
        F1[i] = f2bf(val);
    }
}

// ---------------------------------------------------------------------------
// Stencil + transpose: grid'[b][y][x] = sum_s M9[s][y,x] * c[b][y+dy][x+dx],
// cell (0,0) extracted to g00[b] (fp32 path, re-added in gemm2 epilogue)
// and zeroed. Output B1t[(b*320+x)][y'] bf16 (k-contiguous for stage 1).
// ---------------------------------------------------------------------------
__global__ __launch_bounds__(256) void stencil_t(const float2* __restrict__ ksp,
                                                 const float* __restrict__ M9,
                                                 short* __restrict__ B1t,
                                                 float* __restrict__ g00) {
    __shared__ float2 Ls[32][33];
    int b = blockIdx.z;
    int tx0 = blockIdx.x * 32, ty0 = blockIdx.y * 32;
    int tid = threadIdx.x;
    int xl = tid & 31, yq = tid >> 5;
    const float2* kb = ksp + (size_t)b * CELLS;
#pragma unroll
    for (int rr = 0; rr < 4; rr++) {
        int yl = yq + 8 * rr;
        int y = ty0 + yl, x = tx0 + xl;
        int cell = y * RES + x;
        float re = 0.f, im = 0.f;
#pragma unroll
        for (int s = 0; s < 9; s++) {
            float w = M9[s * CELLS + cell];
            int dy = s / 3 - 1, dx = s % 3 - 1;
            int yn = min(max(y + dy, 0), RES - 1);
            int xn = min(max(x + dx, 0), RES - 1);
            float2 v = kb[yn * RES + xn];
            re = fmaf(w, v.x, re);
            im = fmaf(w, v.y, im);
        }
        if (cell == 0) {
            g00[2 * b] = re;
            g00[2 * b + 1] = im;
            re = 0.f;
            im = 0.f;
        }
        Ls[yl][xl] = make_float2(re, im);
    }
    __syncthreads();
    int xc = tid >> 3, yg = tid & 7;
    float2 v0 = Ls[yg * 4 + 0][xc], v1 = Ls[yg * 4 + 1][xc];
    float2 v2 = Ls[yg * 4 + 2][xc], v3 = Ls[yg * 4 + 3][xc];
    uint2 pr, pi;
    pr.x = (unsigned short)f2bf(v0.x) | ((unsigned)(unsigned short)f2bf(v1.x) << 16);
    pr.y = (unsigned short)f2bf(v2.x) | ((unsigned)(unsigned short)f2bf(v3.x) << 16);
    pi.x = (unsigned short)f2bf(v0.y) | ((unsigned)(unsigned short)f2bf(v1.y) << 16);
    pi.y = (unsigned short)f2bf(v2.y) | ((unsigned)(unsigned short)f2bf(v3.y) << 16);
    size_t rowbase = ((size_t)b * RES + tx0 + xc) * MDIM;
    *(uint2*)(B1t + rowbase + ty0 + yg * 4) = pr;
    *(uint2*)(B1t + rowbase + RES + ty0 + yg * 4) = pi;
}

// ---------------------------------------------------------------------------
// Stage 1: C1[m'][(b,x)] = sum_y' F1[m'][y'] * B1t[(b,x)][y']
// M=640, N=10240, K=640. 64x128 tile, BK=32, 4 waves x (2x4) 16x16x32 frags.
// Grid: x = m-tile (10, fastest) so consecutive blocks share one B-tile and
// the co-resident window's B footprint (~8.5 MB) stays L2-resident ->
// B1t read from HBM ~once instead of 10x.
// ---------------------------------------------------------------------------
__global__ __launch_bounds__(256) void gemm1(const short* __restrict__ F1,
                                             const short* __restrict__ B1t,
                                             short* __restrict__ C1) {
    __shared__ short At[64 * 32];
    __shared__ short Bt[128 * 32];
    int tid = threadIdx.x;
    int lane = tid & 63, wave = tid >> 6;
    int wr = wave >> 1, wc = wave & 1;
    int m0 = blockIdx.x * 64, n0 = blockIdx.y * 128;
    int q = lane >> 4, tl = lane & 15;
    f32x4 acc[2][4];
#pragma unroll
    for (int i = 0; i < 2; i++)
#pragma unroll
        for (int j = 0; j < 4; j++) acc[i][j] = {0.f, 0.f, 0.f, 0.f};

    for (int kt = 0; kt < 20; kt++) {
        int k0 = kt * 32;
        {
            int row = tid >> 2, koff = (tid & 3) * 8;
            GLD16(F1 + (size_t)(m0 + row) * MDIM + k0 + koff,
                  At + (size_t)(wave * 64) * 8);
        }
#pragma unroll
        for (int r = 0; r < 2; r++) {
            int c = r * 256 + tid;
            int row = c >> 2, koff = (c & 3) * 8;
            GLD16(B1t + (size_t)(n0 + row) * MDIM + k0 + koff,
                  Bt + (size_t)(r * 256 + wave * 64) * 8);
        }
        __syncthreads();
        short8 a[2], bf[4];
#pragma unroll
        for (int i = 0; i < 2; i++)
            a[i] = *(const short8*)&At[(wr * 32 + i * 16 + tl) * 32 + q * 8];
#pragma unroll
        for (int j = 0; j < 4; j++)
            bf[j] = *(const short8*)&Bt[(wc * 64 + j * 16 + tl) * 32 + q * 8];
#pragma unroll
        for (int i = 0; i < 2; i++)
#pragma unroll
            for (int j = 0; j < 4; j++)
                acc[i][j] = __builtin_amdgcn_mfma_f32_16x16x32_bf16(a[i], bf[j], acc[i][j], 0, 0, 0);
        __syncthreads();
    }
#pragma unroll
    for (int i = 0; i < 2; i++)
#pragma unroll
        for (int j = 0; j < 4; j++)
#pragma unroll
            for (int t = 0; t < 4; t++) {
                int mrow = m0 + wr * 32 + i * 16 + q * 4 + t;
                int ncol = n0 + wc * 64 + j * 16 + tl;
                C1[(size_t)mrow * NCOLS + ncol] = f2bf(acc[i][j][t]);
            }
}

// ---------------------------------------------------------------------------
// Stage 2: out[(b,m)][n'] = sum_x' T2[(b,m)][x'] * F1[n'][x'], with
// T2[(b,m)][x+320*ct] = C1[m+320*ct][b*320+x]. 128x64 tile; grid x = n-tile
// (10, fastest) -> consecutive blocks share the C1 A-tile (L2-resident).
// Epilogue adds g00[b]*(-1)^(m+n) and writes planar out (b,1,2,H,W).
// ---------------------------------------------------------------------------
__global__ __launch_bounds__(256) void gemm2(const short* __restrict__ C1,
                                             const short* __restrict__ F1,
                                             const float* __restrict__ g00,
                                             float* __restrict__ out) {
    __shared__ short At[128 * 32];
    __shared__ short Bt[64 * 32];
    int tid = threadIdx.x;
    int lane = tid & 63, wave = tid >> 6;
    int wr = wave >> 1, wc = wave & 1;
    int r0 = blockIdx.y * 128, n0 = blockIdx.x * 64;
    int q = lane >> 4, tl = lane & 15;
    f32x4 acc[4][2];
#pragma unroll
    for (int i = 0; i < 4; i++)
#pragma unroll
        for (int j = 0; j < 2; j++) acc[i][j] = {0.f, 0.f, 0.f, 0.f};

    for (int kt = 0; kt < 20; kt++) {
        int k0 = kt * 32;
        int ct = (k0 >= RES) ? 1 : 0;
        int kk = k0 - RES * ct;
#pragma unroll
        for (int r = 0; r < 2; r++) {
            int c = r * 256 + tid;
            int row = c >> 2, koff = (c & 3) * 8;
            int gr = r0 + row;
            unsigned bb = (unsigned)gr / 320u;
            int m = gr - (int)bb * 320;
            GLD16(C1 + (size_t)(m + RES * ct) * NCOLS + bb * RES + kk + koff,
                  At + (size_t)(r * 256 + wave * 64) * 8);
        }
        {
            int row = tid >> 2, koff = (tid & 3) * 8;
            GLD16(F1 + (size_t)(n0 + row) * MDIM + k0 + koff,
                  Bt + (size_t)(wave * 64) * 8);
        }
        __syncthreads();
        short8 a[4], bf[2];
#pragma unroll
        for (int i = 0; i < 4; i++)
            a[i] = *(const short8*)&At[(wr * 64 + i * 16 + tl) * 32 + q * 8];
#pragma unroll
        for (int j = 0; j < 2; j++)
            bf[j] = *(const short8*)&Bt[(wc * 32 + j * 16 + tl) * 32 + q * 8];
#pragma unroll
        for (int i = 0; i < 4; i++)
#pragma unroll
            for (int j = 0; j < 2; j++)
                acc[i][j] = __builtin_amdgcn_mfma_f32_16x16x32_bf16(a[i], bf[j], acc[i][j], 0, 0, 0);
        __syncthreads();
    }
#pragma unroll
    for (int i = 0; i < 4; i++)
#pragma unroll
        for (int j = 0; j < 2; j++) {
            int npcol = n0 + wc * 32 + j * 16 + tl;
            int comp = npcol >= RES;
            int n = npcol - RES * comp;
#pragma unroll
            for (int t = 0; t < 4; t++) {
                int gr = r0 + wr * 64 + i * 16 + q * 4 + t;
                unsigned bb = (unsigned)gr / 320u;
                int m = gr - (int)bb * 320;
                float g = g00[2 * bb + comp];
                float sgn = ((m + n) & 1) ? -1.0f : 1.0f;
                out[(((size_t)bb * 2 + comp) * RES + m) * RES + n] = acc[i][j][t] + sgn * g;
            }
        }
}

extern "C" void kernel_launch(void* const* d_in, const int* in_sizes, int n_in,
                              void* d_out, int out_size, void* d_ws, size_t ws_size,
                              hipStream_t stream) {
    const float* ksp = (const float*)d_in[0];
    const float* traj = (const float*)d_in[1];

    // Workspace (floats): M9 9*CELLS | M9s 9*CELLS | hal0 9*CELLS | hal1 9*CELLS
    //                     | F1 (bf16) | B1t (bf16) | C1 (bf16) | g00
    float* ws = (float*)d_ws;
    float* M9 = ws;
    float* M9s = ws + (size_t)9 * CELLS;
    float* hal0 = ws + (size_t)18 * CELLS;
    float* hal1 = ws + (size_t)27 * CELLS;
    short* F1 = (short*)(ws + (size_t)36 * CELLS);
    short* B1t = F1 + (size_t)MDIM * MDIM;
    short* C1 = B1t + (size_t)NCOLS * MDIM;
    float* g00 = (float*)(C1 + (size_t)NCOLS * MDIM);

    hipMemsetAsync(M9s, 0, (size_t)9 * CELLS * sizeof(float), stream);
    build_m9<<<RES, 320, 0, stream>>>(traj, hal0, hal1, M9s);
    merge_m9_F1<<<(9 * CELLS + 255) / 256, 256, 0, stream>>>(M9, hal0, hal1, M9s, F1);
    stencil_t<<<dim3(10, 10, 32), 256, 0, stream>>>((const float2*)ksp, M9, B1t, g00);
    gemm1<<<dim3(10, 80), 256, 0, stream>>>(F1, B1t, C1);
    gemm2<<<dim3(10, 80), 256, 0, stream>>>(C1, F1, g00, (float*)d_out);
}

// Round 7
// 154.910 us; speedup vs baseline: 1.0387x; 1.0387x over previous
//
#include <hip/hip_runtime.h>

#define RES 320
#define CELLS (RES * RES)
#define MDIM 640      // 2*RES (Re/Im stacked)
#define NCOLS 10240   // 32 batches * RES

typedef __attribute__((ext_vector_type(8))) short short8;
typedef __attribute__((ext_vector_type(4))) float f32x4;

// round-to-nearest-even f32 -> bf16 bits (all values finite here)
static __device__ __forceinline__ short f2bf(float f) {
    unsigned u = __builtin_bit_cast(unsigned, f);
    unsigned r = (u + 0x7fffu + ((u >> 16) & 1u)) >> 16;
    return (short)r;
}

#define GLD16(g, l) __builtin_amdgcn_global_load_lds(                        \
    (const __attribute__((address_space(1))) void*)(g),                      \
    (__attribute__((address_space(3))) void*)(l), 16, 0, 0)

// ---------------------------------------------------------------------------
// Wave-level run-segmented atomic add: combines contiguous equal-key runs,
// one atomic per run (key < 0 => no atomic). Convergent call required.
// ---------------------------------------------------------------------------
__device__ __forceinline__ void seg_atomic_add(float* base, int key, float val, int lane) {
    int prev = __shfl_up(key, 1);
    bool head = (lane == 0) || (prev != key);
    unsigned long long hb = __ballot(head);
    unsigned long long below = (lane == 63) ? hb : (hb & ((1ULL << (lane + 1)) - 1ULL));
    int run_start = 63 - __clzll(below);
#pragma unroll
    for (int d = 1; d < 64; d <<= 1) {
        float o = __shfl_up(val, d);
        if (lane - d >= run_start) val += o;
    }
    bool tail = (lane == 63) || ((hb >> (lane + 1)) & 1ULL);
    if (tail && key >= 0) atomicAdd(base + key, val);
}

// ---------------------------------------------------------------------------
// Zero the spill plane M9s and generate F1 (one pass, disjoint ranges).
// F1[m'][y'] bf16, 640x640: block matrix [[Fr,-Fi],[Fi,Fr]] of
// F[u,y] = (-1)^(u+y) exp(+2*pi*i*u*y/RES); stage-1 A and stage-2 B operand.
// ---------------------------------------------------------------------------
__global__ __launch_bounds__(256) void make_F1_zero(short* __restrict__ F1,
                                                    float* __restrict__ M9s) {
    int idx = blockIdx.x * 256 + threadIdx.x;
    if (idx < MDIM * MDIM) {
        int mp = idx / MDIM, yp = idx % MDIM;
        int cm = mp >= RES, cy = yp >= RES;
        int m = mp - RES * cm, y = yp - RES * cy;
        int r = (m * y) % RES;
        float s, c;
        sincospif((float)r * (2.0f / RES), &s, &c);
        float sign = ((m + y) & 1) ? -1.0f : 1.0f;
        float fr = sign * c, fi = sign * s;
        float val = (cm == 0) ? (cy == 0 ? fr : -fi) : (cy == 0 ? fi : fr);
        F1[idx] = f2bf(val);
    }
    if (idx < 9 * CELLS) M9s[idx] = 0.f;
}

// ---------------------------------------------------------------------------
// Build M9 pieces, banded NJ=1 + halo planes. Band j (320 blocks): points
// with J=j, thread tid = I. In-bounds targets of normal points have cy in
// {j-1, j} -> LDS window acc[9][2][320]; lanes = consecutive I = consecutive
// cx = conflict-free ds_add. Flush: both window rows to per-band halo planes
// via plain float4 stores (no atomics): hal0[j] = row j-1, hal1[j] = row j.
// Degenerate (skipped-trajectory) contributions go through a ballot-guarded
// convergent seg-atomic into spill plane M9s.
// Final M9[cy] = hal1[cy] + hal0[cy+1] + M9s, composed on the fly in
// stencil_mt (no materialized M9 plane).
// ---------------------------------------------------------------------------
__global__ __launch_bounds__(320) void build_m9(const float* __restrict__ traj,
                                                float* __restrict__ hal0,
                                                float* __restrict__ hal1,
                                                float* __restrict__ M9s) {
    __shared__ float acc[9 * 2 * RES];
    int j = blockIdx.x;     // band = J row
    int tid = threadIdx.x;  // = I
    int lane = tid & 63;
    for (int i = tid; i < 9 * 2 * RES; i += 320) acc[i] = 0.f;
    __syncthreads();

    const float2 t = ((const float2*)traj)[(size_t)tid * RES + j];
    float x = ((t.x * (2.0f / RES) + 1.0f) * RES - 1.0f) * 0.5f;
    float y = ((t.y * (2.0f / RES) + 1.0f) * RES - 1.0f) * 0.5f;
    float x0f = floorf(x), y0f = floorf(y);
    float fx = x - x0f, fy = y - y0f;
    int x0 = (int)x0f, y0 = (int)y0f;

    const int ox[4] = {0, 1, 0, 1};
    const int oy[4] = {0, 0, 1, 1};
    float w[4] = {(1.f - fx) * (1.f - fy), fx * (1.f - fy), (1.f - fx) * fy, fx * fy};
    int cxv[4], cyv[4];
    bool v[4];
#pragma unroll
    for (int k = 0; k < 4; k++) {
        int cx = x0 + ox[k], cy = y0 + oy[k];
        v[k] = (cx >= 0) && (cx < RES) && (cy >= 0) && (cy < RES);
        cxv[k] = cx;
        cyv[k] = cy;
    }
#pragma unroll
    for (int jc = 0; jc < 4; jc++) {
#pragma unroll
        for (int ic = 0; ic < 4; ic++) {
            int slot = (oy[ic] - oy[jc] + 1) * 3 + (ox[ic] - ox[jc] + 1);
            bool valid = v[ic] && v[jc];
            float wv = w[jc] * w[ic];
            int wr = cyv[jc] - j + 1;  // in-window row if 0 or 1
            bool inwin = valid && ((unsigned)wr < 2u);
            if (inwin) atomicAdd(&acc[(slot * 2 + wr) * RES + cxv[jc]], wv);
            bool sp = valid && !inwin;
            if (__ballot(sp))  // wave-uniform guard -> convergent call
                seg_atomic_add(M9s, sp ? slot * CELLS + cyv[jc] * RES + cxv[jc] : -1,
                               wv, lane);
        }
    }
    __syncthreads();
    for (int i = tid; i < 9 * 2 * (RES / 4); i += 320) {
        int q = i % (RES / 4);
        int sr = i / (RES / 4);   // 0..17
        int wrow = sr & 1;
        int slot = sr >> 1;
        float4 v4 = *(const float4*)&acc[(slot * 2 + wrow) * RES + q * 4];
        float* hal = wrow ? hal1 : hal0;
        *(float4*)&hal[((size_t)j * 9 + slot) * RES + q * 4] = v4;
    }
}

// ---------------------------------------------------------------------------
// Fused merge + stencil + transpose, 8 batches per block (grid 10x10x4).
// Phase 1: compose the block's M9 tile (9 slots x 32x32) into LDS from
//          hal1[cy] + hal0[cy+1] + M9s  (float4, coalesced).
// Phase 2: per batch: grid'[b][y][x] = sum_s M9t[s][y,x] * c[b][y+dy][x+dx]
//          (global reads, L1-cached 9x reuse), cell (0,0) extracted to
//          g00[b] fp32 and zeroed; LDS transpose; write
//          B1t[(b*320+x)][y'] bf16 (k-contiguous for stage 1).
// ---------------------------------------------------------------------------
__global__ __launch_bounds__(256) void stencil_mt(const float2* __restrict__ ksp,
                                                  const float* __restrict__ hal0,
                                                  const float* __restrict__ hal1,
                                                  const float* __restrict__ M9s,
                                                  short* __restrict__ B1t,
                                                  float* __restrict__ g00) {
    __shared__ float M9t[9 * 32 * 32];
    __shared__ float2 Ls[32][33];
    int tx0 = blockIdx.x * 32, ty0 = blockIdx.y * 32;
    int tid = threadIdx.x;

    // Phase 1: 9 slots x 256 float4 = 2304 items, 9 iters of 256 threads.
    for (int i = tid; i < 9 * 256; i += 256) {
        int s = i >> 8;
        int r = i & 255;
        int yl = r >> 3, xq = r & 7;
        int cy = ty0 + yl;
        int xg = tx0 + xq * 4;
        float4 a = *(const float4*)&hal1[((size_t)cy * 9 + s) * RES + xg];
        float4 c = *(const float4*)&M9s[(size_t)s * CELLS + (size_t)cy * RES + xg];
        float4 v;
        v.x = a.x + c.x; v.y = a.y + c.y; v.z = a.z + c.z; v.w = a.w + c.w;
        if (cy + 1 < RES) {
            float4 b = *(const float4*)&hal0[((size_t)(cy + 1) * 9 + s) * RES + xg];
            v.x += b.x; v.y += b.y; v.z += b.z; v.w += b.w;
        }
        *(float4*)&M9t[(s * 32 + yl) * 32 + xq * 4] = v;
    }
    __syncthreads();

    int xl = tid & 31, yq = tid >> 5;
    int xc = tid >> 3, yg = tid & 7;
#pragma unroll 1
    for (int b8 = 0; b8 < 8; b8++) {
        int bb = blockIdx.z * 8 + b8;
        const float2* kb = ksp + (size_t)bb * CELLS;
#pragma unroll
        for (int rr = 0; rr < 4; rr++) {
            int yl = yq + 8 * rr;
            int y = ty0 + yl, x = tx0 + xl;
            float re = 0.f, im = 0.f;
#pragma unroll
            for (int s = 0; s < 9; s++) {
                float w = M9t[(s * 32 + yl) * 32 + xl];
                int dy = s / 3 - 1, dx = s % 3 - 1;
                int yn = min(max(y + dy, 0), RES - 1);
                int xn = min(max(x + dx, 0), RES - 1);
                float2 v = kb[yn * RES + xn];
                re = fmaf(w, v.x, re);
                im = fmaf(w, v.y, im);
            }
            if ((y | x) == 0) {  // cell (0,0): exact fp32 rank-1 path
                g00[2 * bb] = re;
                g00[2 * bb + 1] = im;
                re = 0.f;
                im = 0.f;
            }
            Ls[yl][xl] = make_float2(re, im);
        }
        __syncthreads();
        float2 v0 = Ls[yg * 4 + 0][xc], v1 = Ls[yg * 4 + 1][xc];
        float2 v2 = Ls[yg * 4 + 2][xc], v3 = Ls[yg * 4 + 3][xc];
        uint2 pr, pi;
        pr.x = (unsigned short)f2bf(v0.x) | ((unsigned)(unsigned short)f2bf(v1.x) << 16);
        pr.y = (unsigned short)f2bf(v2.x) | ((unsigned)(unsigned short)f2bf(v3.x) << 16);
        pi.x = (unsigned short)f2bf(v0.y) | ((unsigned)(unsigned short)f2bf(v1.y) << 16);
        pi.y = (unsigned short)f2bf(v2.y) | ((unsigned)(unsigned short)f2bf(v3.y) << 16);
        size_t rowbase = ((size_t)bb * RES + tx0 + xc) * MDIM;
        *(uint2*)(B1t + rowbase + ty0 + yg * 4) = pr;
        *(uint2*)(B1t + rowbase + RES + ty0 + yg * 4) = pi;
        __syncthreads();  // Ls reuse fence for next batch
    }
}

// ---------------------------------------------------------------------------
// Stage 1: C1[m'][(b,x)] = sum_y' F1[m'][y'] * B1t[(b,x)][y']
// M=640, N=10240, K=640. 128x128 tile (m97 ratio: 64 FLOP/B staged), BK=32,
// 4 waves x 4x4 16x16x32 MFMA frags. Grid x = n-tile (80) fastest.
// ---------------------------------------------------------------------------
__global__ __launch_bounds__(256) void gemm1(const short* __restrict__ F1,
                                             const short* __restrict__ B1t,
                                             short* __restrict__ C1) {
    __shared__ short At[128 * 32];
    __shared__ short Bt[128 * 32];
    int tid = threadIdx.x;
    int lane = tid & 63, wave = tid >> 6;
    int wr = wave >> 1, wc = wave & 1;
    int m0 = blockIdx.y * 128, n0 = blockIdx.x * 128;
    int q = lane >> 4, tl = lane & 15;
    f32x4 acc[4][4];
#pragma unroll
    for (int i = 0; i < 4; i++)
#pragma unroll
        for (int j = 0; j < 4; j++) acc[i][j] = {0.f, 0.f, 0.f, 0.f};

    for (int kt = 0; kt < 20; kt++) {
        int k0 = kt * 32;
#pragma unroll
        for (int r = 0; r < 2; r++) {
            int c = r * 256 + tid;
            int row = c >> 2, koff = (c & 3) * 8;
            GLD16(F1 + (size_t)(m0 + row) * MDIM + k0 + koff,
                  At + (size_t)(r * 256 + wave * 64) * 8);
            GLD16(B1t + (size_t)(n0 + row) * MDIM + k0 + koff,
                  Bt + (size_t)(r * 256 + wave * 64) * 8);
        }
        __syncthreads();
        short8 a[4], bf[4];
#pragma unroll
        for (int i = 0; i < 4; i++)
            a[i] = *(const short8*)&At[(wr * 64 + i * 16 + tl) * 32 + q * 8];
#pragma unroll
        for (int j = 0; j < 4; j++)
            bf[j] = *(const short8*)&Bt[(wc * 64 + j * 16 + tl) * 32 + q * 8];
#pragma unroll
        for (int i = 0; i < 4; i++)
#pragma unroll
            for (int j = 0; j < 4; j++)
                acc[i][j] = __builtin_amdgcn_mfma_f32_16x16x32_bf16(a[i], bf[j], acc[i][j], 0, 0, 0);
        __syncthreads();
    }
#pragma unroll
    for (int i = 0; i < 4; i++)
#pragma unroll
        for (int j = 0; j < 4; j++)
#pragma unroll
            for (int t = 0; t < 4; t++) {
                int mrow = m0 + wr * 64 + i * 16 + q * 4 + t;
                int ncol = n0 + wc * 64 + j * 16 + tl;
                C1[(size_t)mrow * NCOLS + ncol] = f2bf(acc[i][j][t]);
            }
}

// ---------------------------------------------------------------------------
// Stage 2: out[(b,m)][n'] = sum_x' T2[(b,m)][x'] * F1[n'][x'], with
// T2[(b,m)][x+320*ct] = C1[m+320*ct][b*320+x] (per-lane GLD16 addressing, no
// transpose kernel). 128x128 tile; grid x = n'-tile (5) fastest. Epilogue
// adds the rank-1 checkerboard g00[b]*(-1)^(m+n), writes planar (b,1,2,H,W).
// ---------------------------------------------------------------------------
__global__ __launch_bounds__(256) void gemm2(const short* __restrict__ C1,
                                             const short* __restrict__ F1,
                                             const float* __restrict__ g00,
                                             float* __restrict__ out) {
    __shared__ short At[128 * 32];
    __shared__ short Bt[128 * 32];
    int tid = threadIdx.x;
    int lane = tid & 63, wave = tid >> 6;
    int wr = wave >> 1, wc = wave & 1;
    int r0 = blockIdx.y * 128, n0 = blockIdx.x * 128;
    int q = lane >> 4, tl = lane & 15;
    f32x4 acc[4][4];
#pragma unroll
    for (int i = 0; i < 4; i++)
#pragma unroll
        for (int j = 0; j < 4; j++) acc[i][j] = {0.f, 0.f, 0.f, 0.f};

    for (int kt = 0; kt < 20; kt++) {
        int k0 = kt * 32;
        int ct = (k0 >= RES) ? 1 : 0;
        int kk = k0 - RES * ct;
#pragma unroll
        for (int r = 0; r < 2; r++) {
            int c = r * 256 + tid;
            int row = c >> 2, koff = (c & 3) * 8;
            int gr = r0 + row;
            unsigned bb = (unsigned)gr / 320u;
            int m = gr - (int)bb * 320;
            GLD16(C1 + (size_t)(m + RES * ct) * NCOLS + bb * RES + kk + koff,
                  At + (size_t)(r * 256 + wave * 64) * 8);
            GLD16(F1 + (size_t)(n0 + row) * MDIM + k0 + koff,
                  Bt + (size_t)(r * 256 + wave * 64) * 8);
        }
        __syncthreads();
        short8 a[4], bf[4];
#pragma unroll
        for (int i = 0; i < 4; i++)
            a[i] = *(const short8*)&At[(wr * 64 + i * 16 + tl) * 32 + q * 8];
#pragma unroll
        for (int j = 0; j < 4; j++)
            bf[j] = *(const short8*)&Bt[(wc * 64 + j * 16 + tl) * 32 + q * 8];
#pragma unroll
        for (int i = 0; i < 4; i++)
#pragma unroll
            for (int j = 0; j < 4; j++)
                acc[i][j] = __builtin_amdgcn_mfma_f32_16x16x32_bf16(a[i], bf[j], acc[i][j], 0, 0, 0);
        __syncthreads();
    }
#pragma unroll
    for (int i = 0; i < 4; i++)
#pragma unroll
        for (int j = 0; j < 4; j++) {
            int npcol = n0 + wc * 64 + j * 16 + tl;
            int comp = npcol >= RES;
            int n = npcol - RES * comp;
#pragma unroll
            for (int t = 0; t < 4; t++) {
                int gr = r0 + wr * 64 + i * 16 + q * 4 + t;
                unsigned bb = (unsigned)gr / 320u;
                int m = gr - (int)bb * 320;
                float g = g00[2 * bb + comp];
                float sgn = ((m + n) & 1) ? -1.0f : 1.0f;
                out[(((size_t)bb * 2 + comp) * RES + m) * RES + n] = acc[i][j][t] + sgn * g;
            }
        }
}

extern "C" void kernel_launch(void* const* d_in, const int* in_sizes, int n_in,
                              void* d_out, int out_size, void* d_ws, size_t ws_size,
                              hipStream_t stream) {
    const float* ksp = (const float*)d_in[0];
    const float* traj = (const float*)d_in[1];

    // Workspace (floats): M9s 9*CELLS | hal0 9*CELLS | hal1 9*CELLS
    //                     | F1 (bf16) | B1t (bf16) | C1 (bf16) | g00
    float* ws = (float*)d_ws;
    float* M9s = ws;
    float* hal0 = ws + (size_t)9 * CELLS;
    float* hal1 = ws + (size_t)18 * CELLS;
    short* F1 = (short*)(ws + (size_t)27 * CELLS);
    short* B1t = F1 + (size_t)MDIM * MDIM;
    short* C1 = B1t + (size_t)NCOLS * MDIM;
    float* g00 = (float*)(C1 + (size_t)NCOLS * MDIM);

    make_F1_zero<<<(9 * CELLS + 255) / 256, 256, 0, stream>>>(F1, M9s);
    build_m9<<<RES, 320, 0, stream>>>(traj, hal0, hal1, M9s);
    stencil_mt<<<dim3(10, 10, 4), 256, 0, stream>>>((const float2*)ksp, hal0, hal1,
                                                    M9s, B1t, g00);
    gemm1<<<dim3(80, 5), 256, 0, stream>>>(F1, B1t, C1);
    gemm2<<<dim3(5, 80), 256, 0, stream>>>(C1, F1, g00, (float*)d_out);
}